// Round 16
// baseline (1755.451 us; speedup 1.0000x reference)
//
#include <hip/hip_runtime.h>
#include <hip/hip_fp16.h>
#include <cstddef>

#define TT 2048   // time steps
#define BB 256    // batch
#define DD 32     // input dim
#define HH 64     // hidden
#define GG 256    // 4*H

// 7th-order rational tanh (R15-validated: -170us, absmax unchanged)
__device__ __forceinline__ float tanh_rat(float x) {
    x = fminf(fmaxf(x, -4.97f), 4.97f);
    float x2 = x * x;
    float p = x * fmaf(x2, fmaf(x2, x2 + 378.0f, 17325.0f), 135135.0f);
    float q = fmaf(x2, fmaf(x2, fmaf(x2, 28.0f, 3150.0f), 62370.0f), 135135.0f);
    return p * __builtin_amdgcn_rcpf(q);
}
__device__ __forceinline__ float act(float z, bool istanh) {
    float zin = istanh ? z : 0.5f * z;
    float t = tanh_rat(zin);
    return istanh ? t : fmaf(0.5f, t, 0.5f);
}
__device__ __forceinline__ float sigmf(float v) { return 1.0f / (1.0f + __expf(-v)); }

// ---- cross-lane xor16/xor32 on the VALU via permlane*_swap (gfx950) ----
// __shfl_xor compiles to ds_bpermute/ds_swizzle: LDS-pipe ops (~100cy latency,
// and they contend with the h-exchange reads across 8 waves). permlane*_swap
// is a VALU op (~4cy). With both operands = a, the result pair is
// {rows-of-a duplicated even, rows-of-a duplicated odd}; one cndmask on the
// lane's row parity selects the xor partner. Guarded: falls back to shfl.
__device__ __forceinline__ float lane_xor16(float a, bool odd16) {
#if __has_builtin(__builtin_amdgcn_permlane16_swap)
    int ai = __float_as_int(a);
    auto pr = __builtin_amdgcn_permlane16_swap(ai, ai, false, false);
    int rx = ((const int*)&pr)[0];   // rows {r0,r0,r2,r2} of a
    int ry = ((const int*)&pr)[1];   // rows {r1,r1,r3,r3} of a
    return __int_as_float(odd16 ? rx : ry);
#else
    return __shfl_xor(a, 16, 64);
#endif
}
__device__ __forceinline__ float lane_xor32(float a, bool hi32) {
#if __has_builtin(__builtin_amdgcn_permlane32_swap)
    int ai = __float_as_int(a);
    auto pr = __builtin_amdgcn_permlane32_swap(ai, ai, false, false);
    int rx = ((const int*)&pr)[0];   // {a.lo, a.lo}
    int ry = ((const int*)&pr)[1];   // {a.hi, a.hi}
    return __int_as_float(hi32 ? rx : ry);
#else
    return __shfl_xor(a, 32, 64);
#endif
}

// LDS-only barrier (R13-validated): keeps the global x-prefetch in flight.
#define LDS_BARRIER() asm volatile("s_waitcnt lgkmcnt(0)\n\ts_barrier" ::: "memory")

// One block per batch row; 512 threads = 8 waves (R8/R15 structure).
// Waves 0-3: layer-1 engine (one step ahead). Waves 4-7: layer-2 + projection.
// Thread map: unit u = wid*16 + (l&15), K-quarter kq = l>>4; all 4 gates of u
// over the K-chunk (v_pk_fma_f16); combine + gather now permlane-based (VALU).
__global__ __launch_bounds__(512, 2)
void dlstm_kernel(const float* __restrict__ x,
                  const float* __restrict__ W1, const float* __restrict__ U1,
                  const float* __restrict__ b1,
                  const float* __restrict__ W2, const float* __restrict__ U2,
                  const float* __restrict__ b2,
                  const float* __restrict__ Wd, const float* __restrict__ bd,
                  float* __restrict__ out)
{
    const int tid = threadIdx.x, b = blockIdx.x;
    const int wid = tid >> 6, l = tid & 63;
    const int kq = l >> 4, ul = l & 15;
    const bool istanh = (kq == 2);
    const bool odd16 = (kq & 1);        // row-16 parity of this lane
    const bool hi32  = (kq >= 2);       // upper-half parity of this lane

    __shared__ __align__(16) __half h1b[2][HH];
    __shared__ __align__(16) __half h2b[2][HH];
    __shared__ float pbuf[2][4];

    if (tid < HH) {
        h1b[0][tid] = __float2half(0.f); h1b[1][tid] = __float2half(0.f);
        h2b[0][tid] = __float2half(0.f); h2b[1][tid] = __float2half(0.f);
    }
    if (tid < 8) pbuf[tid >> 2][tid & 3] = 0.f;
    __syncthreads();

    if (wid < 4) {
        // ================= layer-1 engine: computes h1(n) at iter n =================
        const int u = (wid << 4) + ul;
        __half2 u1p[4][8];
        #pragma unroll
        for (int gp = 0; gp < 4; ++gp)
            #pragma unroll
            for (int j = 0; j < 8; ++j)
                u1p[gp][j] = __floats2half2_rn(U1[(kq*16 + 2*j    ) * GG + gp*HH + u],
                                               U1[(kq*16 + 2*j + 1) * GG + gp*HH + u]);
        __half2 w1p[4][4];
        #pragma unroll
        for (int gp = 0; gp < 4; ++gp)
            #pragma unroll
            for (int j = 0; j < 4; ++j)
                w1p[gp][j] = __floats2half2_rn(W1[(kq*8 + 2*j    ) * GG + gp*HH + u],
                                               W1[(kq*8 + 2*j + 1) * GG + gp*HH + u]);
        const float b1k = b1[kq * HH + u];
        const float bd0 = bd[0];
        float c1 = 0.f;

        const float* xr = x + (size_t)b * TT * DD + kq * 8;   // my 8 x-elems
        float4 xa = *(const float4*)(xr);
        float4 xb = *(const float4*)(xr + 4);

        for (int n = 0; n < TT + 2; ++n) {
            const int p = n & 1;
            if (n < TT) {
                const size_t tn = (n + 1 < TT) ? (size_t)(n + 1) : (size_t)n;
                float4 na = *(const float4*)(xr + tn * DD);     // prefetch x(n+1)
                float4 nb = *(const float4*)(xr + tn * DD + 4); // (no vmcnt drain at barrier)

                __half2 xx[4];
                xx[0] = __floats2half2_rn(xa.x, xa.y);
                xx[1] = __floats2half2_rn(xa.z, xa.w);
                xx[2] = __floats2half2_rn(xb.x, xb.y);
                xx[3] = __floats2half2_rn(xb.z, xb.w);

                const __half2* hp = (const __half2*)&h1b[p][kq * 16];
                __half2 hh[8];
                #pragma unroll
                for (int j = 0; j < 8; ++j) hh[j] = hp[j];

                float ag[4];
                #pragma unroll
                for (int gp = 0; gp < 4; ++gp) {
                    __half2 s = __float2half2_rn(0.f);
                    #pragma unroll
                    for (int j = 0; j < 8; ++j) s = __hfma2(u1p[gp][j], hh[j], s);
                    #pragma unroll
                    for (int j = 0; j < 4; ++j) s = __hfma2(w1p[gp][j], xx[j], s);
                    ag[gp] = __low2float(s) + __high2float(s);
                }
                // combine across kq (VALU permlane): lane ends with z of gate kq
                float t1 = odd16 ? ag[0] : ag[1];
                float t2 = odd16 ? ag[2] : ag[3];
                float r1 = lane_xor16(t1, odd16);
                float r2 = lane_xor16(t2, odd16);
                float m1 = odd16 ? ag[1] : ag[0];
                float m2 = odd16 ? ag[3] : ag[2];
                float s1 = m1 + r1, s2 = m2 + r2;
                float t3 = hi32 ? s1 : s2;
                float r3 = lane_xor32(t3, hi32);
                float mine = hi32 ? s2 : s1;
                float z = mine + r3 + b1k;

                float a = act(z, istanh);
                // gather (VALU permlane): a=kq, g16=kq^1, g32=kq^2, g48=kq^3
                float g16 = lane_xor16(a, odd16);
                float g32 = lane_xor32(a, hi32);
                float g48 = lane_xor32(g16, hi32);
                // kq0 roles: i=a(g0) f=g16(g1) c~=g32(g2) o=g48(g3)
                c1 = g16 * c1 + a * g32;
                float h = g48 * tanh_rat(c1);
                if (kq == 0) h1b[p ^ 1][u] = __float2half(h);

                xa = na; xb = nb;
            }
            // out(n-2): partials written by L2 at iter n-1
            if (tid == 0 && n >= 2) {
                float s = pbuf[p][0] + pbuf[p][1] + pbuf[p][2] + pbuf[p][3];
                out[(size_t)b * TT + (n - 2)] = sigmf(s + bd0);
            }
            LDS_BARRIER();
        }
    } else {
        // ================= layer-2 engine: computes h2(n-1) at iter n =================
        const int w2i = wid - 4;
        const int u = (w2i << 4) + ul;
        __half2 w2p[4][8], u2p[4][8];
        #pragma unroll
        for (int gp = 0; gp < 4; ++gp)
            #pragma unroll
            for (int j = 0; j < 8; ++j) {
                w2p[gp][j] = __floats2half2_rn(W2[(kq*16 + 2*j    ) * GG + gp*HH + u],
                                               W2[(kq*16 + 2*j + 1) * GG + gp*HH + u]);
                u2p[gp][j] = __floats2half2_rn(U2[(kq*16 + 2*j    ) * GG + gp*HH + u],
                                               U2[(kq*16 + 2*j + 1) * GG + gp*HH + u]);
            }
        const float b2k = b2[kq * HH + u];
        const float wdu = Wd[u];
        float c2 = 0.f;

        for (int n = 0; n < TT + 2; ++n) {
            const int p = n & 1;
            if (n >= 1 && n <= TT) {
                const __half2* h1p = (const __half2*)&h1b[p][kq * 16];
                const __half2* h2p = (const __half2*)&h2b[p][kq * 16];
                __half2 hh1[8], hh2[8];
                #pragma unroll
                for (int j = 0; j < 8; ++j) { hh1[j] = h1p[j]; hh2[j] = h2p[j]; }

                float ag[4];
                #pragma unroll
                for (int gp = 0; gp < 4; ++gp) {
                    __half2 s = __float2half2_rn(0.f);
                    #pragma unroll
                    for (int j = 0; j < 8; ++j) s = __hfma2(w2p[gp][j], hh1[j], s);
                    #pragma unroll
                    for (int j = 0; j < 8; ++j) s = __hfma2(u2p[gp][j], hh2[j], s);
                    ag[gp] = __low2float(s) + __high2float(s);
                }
                float t1 = odd16 ? ag[0] : ag[1];
                float t2 = odd16 ? ag[2] : ag[3];
                float r1 = lane_xor16(t1, odd16);
                float r2 = lane_xor16(t2, odd16);
                float m1 = odd16 ? ag[1] : ag[0];
                float m2 = odd16 ? ag[3] : ag[2];
                float s1 = m1 + r1, s2 = m2 + r2;
                float t3 = hi32 ? s1 : s2;
                float r3 = lane_xor32(t3, hi32);
                float mine = hi32 ? s2 : s1;
                float z = mine + r3 + b2k;

                float a = act(z, istanh);
                float g16 = lane_xor16(a, odd16);
                float g32 = lane_xor32(a, hi32);
                float g48 = lane_xor32(g16, hi32);
                c2 = g16 * c2 + a * g32;         // kq0 roles
                float h = g48 * tanh_rat(c2);
                if (kq == 0) h2b[p ^ 1][u] = __float2half(h);

                // projection partial (off the h2 critical chain)
                float v = (kq == 0) ? h * wdu : 0.f;
                v += __shfl_xor(v, 1, 64);
                v += __shfl_xor(v, 2, 64);
                v += __shfl_xor(v, 4, 64);
                v += __shfl_xor(v, 8, 64);
                if (l == 0) pbuf[p ^ 1][w2i] = v;
            }
            LDS_BARRIER();
        }
    }
}

extern "C" void kernel_launch(void* const* d_in, const int* in_sizes, int n_in,
                              void* d_out, int out_size, void* d_ws, size_t ws_size,
                              hipStream_t stream) {
    const float* x  = (const float*)d_in[0];
    const float* W1 = (const float*)d_in[1];
    const float* U1 = (const float*)d_in[2];
    const float* b1 = (const float*)d_in[3];
    const float* W2 = (const float*)d_in[4];
    const float* U2 = (const float*)d_in[5];
    const float* b2 = (const float*)d_in[6];
    const float* Wd = (const float*)d_in[7];
    const float* bd = (const float*)d_in[8];
    float* out = (float*)d_out;

    dlstm_kernel<<<dim3(BB), dim3(512), 0, stream>>>(
        x, W1, U1, b1, W2, U2, b2, Wd, bd, out);
}